// Round 9
// baseline (429.189 us; speedup 1.0000x reference)
//
#include <hip/hip_runtime.h>
#include <hip/hip_bf16.h>
#include <stdint.h>

// LimitRegressor = relu(x@W1+b1)@W2+b2 followed by a fixed-point iteration
// whose unique fixed point is y*=out (tanh contraction, global early-exit at
// eps=1e-6 fires at k~13 with residual < 3e-7 << the 6.09e-2 threshold).
// So we emit out directly: two bf16 MFMA GEMMs.
//
// Both GEMMs use the 4-wave ILP structure (256x256 tile, BK=64, per-wave
// 128x128 out via mfma 32x32x16, 256-AGPR acc, 1 wave/SIMD, barrier-free
// {32 ds_read + 64 MFMA} block per K-tile, 2-tile gload_lds prefetch,
// counted VMW(16)). Measured 80us = 1717 TF on GEMM2 (HipKittens-class).
//
// GEMM1 (K=1024, would need 1024 wgs = 4 sequential 1-block/CU rounds, each
// exposing cold prologue + epilogue + teardown = the measured 115us gap) is
// made PERSISTENT: 256 blocks, fixed bn, loop 4 M-tiles in one continuous
// 64-K-tile pipeline; acc flushed at 16-tile boundaries with stores issued
// BEFORE the next stage so the counted VMW(16) (FIFO) never waits on the
// next prefetch. B-panel stays L2-hot across the 4 M-tiles.

#define DEV __device__ __forceinline__

typedef short bf16x8 __attribute__((ext_vector_type(8)));
typedef float f32x16 __attribute__((ext_vector_type(16)));

typedef __attribute__((address_space(1))) const unsigned char* gptr1_t;
typedef __attribute__((address_space(3))) unsigned char* lptr3_t;

DEV void async_copy16(const void* g, void* l) {
  __builtin_amdgcn_global_load_lds((gptr1_t)g, (lptr3_t)l, 16, 0, 0);
}

DEV unsigned short f2bf(float f) {
  union { float f; unsigned u; } v; v.f = f;
  unsigned u = v.u + 0x7FFFu + ((v.u >> 16) & 1u);  // RNE
  return (unsigned short)(u >> 16);
}

#define BAR()    __builtin_amdgcn_s_barrier()
#define VMW(n)   asm volatile("s_waitcnt vmcnt(" #n ")" ::: "memory")
#define SCHEDB() __builtin_amdgcn_sched_barrier(0)

// ---------------- prep kernels ----------------

__global__ void cvt_f32_bf16(const float4* __restrict__ in,
                             ushort4* __restrict__ out, int n4) {
  int i = blockIdx.x * blockDim.x + threadIdx.x;
  if (i >= n4) return;
  float4 v = in[i];
  ushort4 o;
  o.x = f2bf(v.x); o.y = f2bf(v.y); o.z = f2bf(v.z); o.w = f2bf(v.w);
  out[i] = o;
}

// f32 [R][C] row-major  ->  bf16 [C][R] row-major (W -> W^T as bf16)
__global__ void transpose_f32_bf16(const float* __restrict__ in,
                                   unsigned short* __restrict__ out,
                                   int R, int C) {
  __shared__ float tile[32][33];
  int c0 = blockIdx.x * 32, r0 = blockIdx.y * 32;
  int tx = threadIdx.x, ty = threadIdx.y;  // block (32, 8)
#pragma unroll
  for (int i = 0; i < 32; i += 8)
    tile[ty + i][tx] = in[(long)(r0 + ty + i) * C + (c0 + tx)];
  __syncthreads();
#pragma unroll
  for (int i = 0; i < 32; i += 8)
    out[(long)(c0 + ty + i) * R + (r0 + tx)] = f2bf(tile[tx][ty + i]);
}

// ---------------- shared ILP4 building blocks ----------------
// LDS per operand per buf: [256 rows][64 k] bf16 = 32KB, 8 x 16B chunks/row,
// chunk swizzle f(r) = (r&7) ^ ((r>>3)&3): LDS[row][p] = global chunk
// p ^ f(row). Pre-swizzled global source (both-sides rule). 0 conflicts
// measured (round 8).

#define ILDA(base, m, ks) \
  (*(const bf16x8*)((base) + i_abase + (m) * 4096 + (i_c0 ^ ((ks) << 5))))
#define ILDB(base, n, ks) \
  (*(const bf16x8*)((base) + i_bbase + (n) * 4096 + (i_c0 ^ ((ks) << 5))))

#define ICOMPUTE(aB, bB)                                                      \
  _Pragma("unroll") for (int ks = 0; ks < 4; ++ks) {                          \
    bf16x8 af[4], bfr[4];                                                     \
    _Pragma("unroll") for (int i = 0; i < 4; ++i) {                           \
      af[i] = ILDA(aB, i, ks);                                                \
      bfr[i] = ILDB(bB, i, ks);                                               \
    }                                                                         \
    _Pragma("unroll") for (int m_ = 0; m_ < 4; ++m_)                          \
    _Pragma("unroll") for (int n_ = 0; n_ < 4; ++n_)                          \
      acc[m_][n_] = __builtin_amdgcn_mfma_f32_32x32x16_bf16(                  \
          af[m_], bfr[n_], acc[m_][n_], 0, 0, 0);                             \
  }

// ================= Kernel A: persistent ILP4 (GEMM1) ======================
// 256 blocks; block: bn fixed (16 values), grp = swz>>4 (16), loops j=0..3
// over M-tiles m0 = grp*1024 + j*256. One continuous 64-tile pipeline.

#define PSTAGE(buf_, g_)                                                      \
  { const int t_ = (g_) & 15;                                                 \
    const size_t ja_ = (size_t)((g_) >> 4) * ((size_t)K << 8);                \
    _Pragma("unroll") for (int j = 0; j < 8; ++j) {                           \
      async_copy16(gAb + ja_ + (size_t)j * 32 * K + (t_ << 6),                \
                   ldsAw + (buf_) * 32768 + j * 4096);                        \
      async_copy16(gBb + (size_t)j * 32 * K + (t_ << 6),                      \
                   ldsBw + (buf_) * 32768 + j * 4096);                        \
    } }

#define PEPI(j_)                                                              \
  { const size_t crow = (size_t)m0base + (size_t)(j_) * 256 + wr * 128;       \
    _Pragma("unroll") for (int m = 0; m < 4; ++m)                             \
    _Pragma("unroll") for (int rr = 0; rr < 4; ++rr)                          \
    _Pragma("unroll") for (int q = 0; q < 4; ++q) {                           \
      size_t r = (crow + m * 32 + lg2 * 4 + q + 8 * rr) * Ndim;               \
      _Pragma("unroll") for (int n = 0; n < 4; ++n) {                         \
        float v = acc[m][n][rr * 4 + q] + bv[n];                              \
        O[r + ccol + n * 32 + cl31] = f2bf(fmaxf(v, 0.0f));                   \
      } } }

#define ZEROACC()                                                             \
  _Pragma("unroll") for (int m = 0; m < 4; ++m)                               \
  _Pragma("unroll") for (int n = 0; n < 4; ++n)                               \
  _Pragma("unroll") for (int e = 0; e < 16; ++e) acc[m][n][e] = 0.0f;

__global__ __launch_bounds__(256, 1)
void gemm_ilp4p(const unsigned short* __restrict__ A,   // bf16 [16384][K]
                const unsigned short* __restrict__ BT,  // bf16 [Ndim][K]
                const float* __restrict__ bias,         // [Ndim]
                unsigned short* __restrict__ O,         // bf16 [16384][Ndim]
                int Kd, int Ndim) {
  extern __shared__ char lds[];
  char* ldsA = lds;             // [2][32768]
  char* ldsB = lds + 65536;     // [2][32768]
  const int K = Kd;             // 1024

  const int tid = threadIdx.x;
  const int wave = tid >> 6, lane = tid & 63;
  const int wr = wave >> 1, wc = wave & 1;  // 2x2 waves, each 128x128 out

  // XCD swizzle over 256 wgs; bn = swz&15 (N=4096 -> 16 tiles), grp = swz>>4
  const int nwg = gridDim.x;
  const int wg = blockIdx.x;
  const int swz = (wg & 7) * (nwg >> 3) + (wg >> 3);
  const int bn = swz & 15;
  const int grp = swz >> 4;
  const int n0 = bn << 8;
  const int m0base = grp << 10;   // grp * 4 * 256 rows

  // staging bases
  const int srow = lane >> 3;
  const int skb = (((lane & 7) ^ srow ^ wave) << 3);
  const unsigned short* gAb = A + (size_t)(m0base + wave * 8 + srow) * K + skb;
  const unsigned short* gBb = BT + (size_t)(n0 + wave * 8 + srow) * K + skb;
  char* ldsAw = ldsA + wave * 1024;
  char* ldsBw = ldsB + wave * 1024;

  // fragment read bases
  const int cl31 = lane & 31, lg2 = lane >> 5;
  const int i_c0 = ((lg2 ^ (lane & 7) ^ ((lane >> 3) & 3)) << 4);
  const int i_abase = (wr * 128 + cl31) * 128;
  const int i_bbase = (wc * 128 + cl31) * 128;
  const int ccol = n0 + wc * 128;

  f32x16 acc[4][4] = {};
  float bv[4];
#pragma unroll
  for (int n = 0; n < 4; ++n) bv[n] = bias[ccol + n * 32 + cl31];

  // prologue: tiles 0,1
  PSTAGE(0, 0);
  PSTAGE(1, 1);
  VMW(16);
  BAR();

  // continuous pipeline over 64 global tiles (4 output tiles x 16 K-tiles)
  for (int g = 0; g < 62; ++g) {
    const char* aB = ldsA + (g & 1) * 32768;
    const char* bB = ldsB + (g & 1) * 32768;
    ICOMPUTE(aB, bB);
    BAR();
    if ((g & 15) == 15) {           // output-tile boundary: flush acc
      PEPI(g >> 4);                 // stores issue BEFORE next stage (FIFO)
      ZEROACC();
    }
    SCHEDB();
    PSTAGE(g & 1, g + 2);
    VMW(16);                        // drains tile g+1 (+ boundary stores)
    BAR();
  }
  // tail: tiles 62, 63
  ICOMPUTE(ldsA, ldsB);
  BAR();
  VMW(0);
  BAR();
  ICOMPUTE((ldsA + 32768), (ldsB + 32768));
  PEPI(3);
}

// ================= Kernel B: plain ILP4 (GEMM2, 1 round) ==================

#define ISTAGE(buf_, koff_)                                                   \
  _Pragma("unroll") for (int j = 0; j < 8; ++j) {                             \
    async_copy16(gAb + (size_t)j * 32 * K + (koff_),                          \
                 ldsAw + (buf_) * 32768 + j * 4096);                          \
    async_copy16(gBb + (size_t)j * 32 * K + (koff_),                          \
                 ldsBw + (buf_) * 32768 + j * 4096);                          \
  }

template <bool RELU_BF16>
__global__ __launch_bounds__(256, 1)
void gemm_ilp4(const unsigned short* __restrict__ A,   // bf16 [M][K]
               const unsigned short* __restrict__ BT,  // bf16 [N][K]
               const float* __restrict__ bias,         // [N]
               void* __restrict__ Cout,                // bf16 or f32 [M][N]
               int M, int N, int K, int nbn_shift) {
  extern __shared__ char lds[];
  char* ldsA = lds;             // [2][32768]
  char* ldsB = lds + 65536;     // [2][32768]

  const int tid = threadIdx.x;
  const int wave = tid >> 6, lane = tid & 63;
  const int wr = wave >> 1, wc = wave & 1;  // 2x2 waves, each 128x128 out

  const int nwg = gridDim.x;
  const int wg = blockIdx.x;
  const int swz = (wg & 7) * (nwg >> 3) + (wg >> 3);
  const int bm = swz >> nbn_shift;
  const int bn = swz & ((1 << nbn_shift) - 1);
  const int m0 = bm << 8, n0 = bn << 8;

  const int srow = lane >> 3;
  const int skb = (((lane & 7) ^ srow ^ wave) << 3);
  const unsigned short* gAb = A + (size_t)(m0 + wave * 8 + srow) * K + skb;
  const unsigned short* gBb = BT + (size_t)(n0 + wave * 8 + srow) * K + skb;
  char* ldsAw = ldsA + wave * 1024;
  char* ldsBw = ldsB + wave * 1024;

  const int cl31 = lane & 31, lg2 = lane >> 5;
  const int i_c0 = ((lg2 ^ (lane & 7) ^ ((lane >> 3) & 3)) << 4);
  const int i_abase = (wr * 128 + cl31) * 128;
  const int i_bbase = (wc * 128 + cl31) * 128;

  f32x16 acc[4][4] = {};

  ISTAGE(0, 0);
  ISTAGE(1, 64);
  VMW(16);
  BAR();

  const int NT = K >> 6;

  for (int t = 0; t < NT - 2; ++t) {
    const char* aB = ldsA + (t & 1) * 32768;
    const char* bB = ldsB + (t & 1) * 32768;
    ICOMPUTE(aB, bB);
    BAR();
    SCHEDB();
    ISTAGE(t & 1, (t + 2) << 6);
    VMW(16);
    BAR();
  }
  ICOMPUTE(ldsA, ldsB);
  BAR();
  VMW(0);
  BAR();
  ICOMPUTE((ldsA + 32768), (ldsB + 32768));

  // epilogue: 32x32 C/D: col = lane&31, row = (r&3) + 8*(r>>2) + 4*(l>>5)
  const int ccol = n0 + wc * 128;
  const int crow = m0 + wr * 128;
  float bv[4];
#pragma unroll
  for (int n = 0; n < 4; ++n) bv[n] = bias[ccol + n * 32 + cl31];

  if (RELU_BF16) {
    unsigned short* O = (unsigned short*)Cout;
#pragma unroll
    for (int m = 0; m < 4; ++m)
#pragma unroll
      for (int rr = 0; rr < 4; ++rr)
#pragma unroll
        for (int q = 0; q < 4; ++q) {
          size_t r = (size_t)(crow + m * 32 + lg2 * 4 + q + 8 * rr) * N;
#pragma unroll
          for (int n = 0; n < 4; ++n) {
            float v = acc[m][n][rr * 4 + q] + bv[n];
            O[r + ccol + n * 32 + cl31] = f2bf(fmaxf(v, 0.0f));
          }
        }
  } else {
    float* O = (float*)Cout;
#pragma unroll
    for (int m = 0; m < 4; ++m)
#pragma unroll
      for (int rr = 0; rr < 4; ++rr)
#pragma unroll
        for (int q = 0; q < 4; ++q) {
          size_t r = (size_t)(crow + m * 32 + lg2 * 4 + q + 8 * rr) * N;
#pragma unroll
          for (int n = 0; n < 4; ++n)
            O[r + ccol + n * 32 + cl31] = acc[m][n][rr * 4 + q] + bv[n];
        }
  }
}

// ---------------- launch ----------------

extern "C" void kernel_launch(void* const* d_in, const int* in_sizes, int n_in,
                              void* d_out, int out_size, void* d_ws,
                              size_t ws_size, hipStream_t stream) {
  const float* x  = (const float*)d_in[0];   // [16384,1024]
  const float* W1 = (const float*)d_in[1];   // [1024,4096]
  const float* b1 = (const float*)d_in[2];   // [4096]
  const float* W2 = (const float*)d_in[3];   // [4096,1024]
  const float* b2 = (const float*)d_in[4];   // [1024]
  float* out = (float*)d_out;                // [16384,1024] f32

  const int B = 16384, DIN = 1024, DH = 4096, DOUT = 1024;

  size_t need = (size_t)B * DIN * 2 + (size_t)DIN * DH * 2 +
                (size_t)DH * DOUT * 2 + (size_t)B * DH * 2;
  if (ws_size < need) return;

  char* ws = (char*)d_ws;
  unsigned short* xb  = (unsigned short*)ws;  ws += (size_t)B * DIN * 2;
  unsigned short* w1t = (unsigned short*)ws;  ws += (size_t)DIN * DH * 2;  // [DH][DIN]
  unsigned short* w2t = (unsigned short*)ws;  ws += (size_t)DH * DOUT * 2; // [DOUT][DH]
  unsigned short* h   = (unsigned short*)ws;                               // [B][DH]

  hipFuncSetAttribute((const void*)gemm_ilp4p,
                      hipFuncAttributeMaxDynamicSharedMemorySize, 131072);
  hipFuncSetAttribute((const void*)gemm_ilp4<false>,
                      hipFuncAttributeMaxDynamicSharedMemorySize, 131072);

  int n4 = B * DIN / 4;
  cvt_f32_bf16<<<n4 / 256, 256, 0, stream>>>((const float4*)x, (ushort4*)xb, n4);
  transpose_f32_bf16<<<dim3(DH / 32, DIN / 32), dim3(32, 8), 0, stream>>>(W1, w1t, DIN, DH);
  transpose_f32_bf16<<<dim3(DOUT / 32, DH / 32), dim3(32, 8), 0, stream>>>(W2, w2t, DH, DOUT);

  // h = relu(x @ W1 + b1) : persistent, 256 wgs x 4 M-tiles, K=1024
  gemm_ilp4p<<<dim3(256), 256, 131072, stream>>>(xb, w1t, b1, h, DIN, DH);
  // out = h @ W2 + b2     : M=16384, N=1024, K=4096 (NT=64), 256 wgs
  gemm_ilp4<false><<<dim3((B / 256) * (DOUT / 256)), 256, 131072, stream>>>(
      h, w2t, b2, out, B, DOUT, DH, 2);
}

// Round 10
// 294.255 us; speedup vs baseline: 1.4586x; 1.4586x over previous
//
#include <hip/hip_runtime.h>
#include <hip/hip_bf16.h>
#include <stdint.h>

// LimitRegressor = relu(x@W1+b1)@W2+b2 followed by a fixed-point iteration
// whose unique fixed point is y*=out (tanh contraction, global early-exit at
// eps=1e-6 fires at k~13 with residual < 3e-7 << the 6.09e-2 threshold).
// So we emit out directly: two bf16 MFMA GEMMs, composed from the fastest
// MEASURED structure for each regime (round-9 ledger):
//  - GEMM1 (K=1024, NT=16, 1024 wgs): 8-wave 2-phase kernel, 16x16x32 MFMA,
//    2 blocks/CU overlap prologue/epilogue across rounds. 151us measured.
//    (ilp4 here = 195us: 4 sequential 1-block/CU rounds expose pipeline
//    fill/drain; persistent variant spilled: in-loop epilogue + pipeline
//    state > 256-reg cap.)
//  - GEMM2 (K=4096, NT=64, 256 wgs = one round): 4-wave ILP kernel,
//    32x32x16 MFMA, 256-AGPR acc, 1 wave/SIMD, barrier-free
//    {32 ds_read + 64 MFMA} per K-tile. 80us = 1717 TF measured.

#define DEV __device__ __forceinline__

typedef short bf16x8 __attribute__((ext_vector_type(8)));
typedef float f32x4 __attribute__((ext_vector_type(4)));
typedef float f32x16 __attribute__((ext_vector_type(16)));

typedef __attribute__((address_space(1))) const unsigned char* gptr1_t;
typedef __attribute__((address_space(3))) unsigned char* lptr3_t;

DEV void async_copy16(const void* g, void* l) {
  __builtin_amdgcn_global_load_lds((gptr1_t)g, (lptr3_t)l, 16, 0, 0);
}

DEV unsigned short f2bf(float f) {
  union { float f; unsigned u; } v; v.f = f;
  unsigned u = v.u + 0x7FFFu + ((v.u >> 16) & 1u);  // RNE
  return (unsigned short)(u >> 16);
}

#define BAR()    __builtin_amdgcn_s_barrier()
#define VMW(n)   asm volatile("s_waitcnt vmcnt(" #n ")" ::: "memory")
#define SCHEDB() __builtin_amdgcn_sched_barrier(0)

// ---------------- prep kernels ----------------

__global__ void cvt_f32_bf16(const float4* __restrict__ in,
                             ushort4* __restrict__ out, int n4) {
  int i = blockIdx.x * blockDim.x + threadIdx.x;
  if (i >= n4) return;
  float4 v = in[i];
  ushort4 o;
  o.x = f2bf(v.x); o.y = f2bf(v.y); o.z = f2bf(v.z); o.w = f2bf(v.w);
  out[i] = o;
}

// f32 [R][C] row-major  ->  bf16 [C][R] row-major (W -> W^T as bf16)
__global__ void transpose_f32_bf16(const float* __restrict__ in,
                                   unsigned short* __restrict__ out,
                                   int R, int C) {
  __shared__ float tile[32][33];
  int c0 = blockIdx.x * 32, r0 = blockIdx.y * 32;
  int tx = threadIdx.x, ty = threadIdx.y;  // block (32, 8)
#pragma unroll
  for (int i = 0; i < 32; i += 8)
    tile[ty + i][tx] = in[(long)(r0 + ty + i) * C + (c0 + tx)];
  __syncthreads();
#pragma unroll
  for (int i = 0; i < 32; i += 8)
    out[(long)(c0 + ty + i) * R + (r0 + tx)] = f2bf(tile[tx][ty + i]);
}

// ================= Kernel A: 8-wave 2-phase GEMM (GEMM1) ==================
// 256x256 tile, BK=64, 8 waves (2Mx4N), mfma 16x16x32, dbuf 128KiB LDS,
// two phases/tile, counted VMW(4), chunk-XOR swizzle (0 conflicts measured).
// Round-6 verbatim (151us on GEMM1).

#define LDA(base, m, ks) \
  (*(const bf16x8*)((base) + abase + (m) * 2048 + (c0 ^ ((ks) << 6))))
#define LDB(base, n, ks) \
  (*(const bf16x8*)((base) + bbase + (n) * 2048 + (c0 ^ ((ks) << 6))))

#define RD_A(dst, base, m0_)                                   \
  _Pragma("unroll") for (int m_ = 0; m_ < 4; ++m_) {           \
    dst[m_][0] = LDA(base, (m0_) + m_, 0);                     \
    dst[m_][1] = LDA(base, (m0_) + m_, 1);                     \
  }
#define RD_B(dst, base, n0_)                                   \
  _Pragma("unroll") for (int n_ = 0; n_ < 2; ++n_) {           \
    dst[n_][0] = LDB(base, (n0_) + n_, 0);                     \
    dst[n_][1] = LDB(base, (n0_) + n_, 1);                     \
  }

#define QUAD(MB, NB, AF, BF)                                                \
  do {                                                                      \
    __builtin_amdgcn_s_setprio(1);                                          \
    _Pragma("unroll") for (int m_ = 0; m_ < 4; ++m_)                        \
    _Pragma("unroll") for (int n_ = 0; n_ < 2; ++n_) {                      \
      acc[(MB) + m_][(NB) + n_] = __builtin_amdgcn_mfma_f32_16x16x32_bf16(  \
          AF[m_][0], BF[n_][0], acc[(MB) + m_][(NB) + n_], 0, 0, 0);        \
      acc[(MB) + m_][(NB) + n_] = __builtin_amdgcn_mfma_f32_16x16x32_bf16(  \
          AF[m_][1], BF[n_][1], acc[(MB) + m_][(NB) + n_], 0, 0, 0);        \
    }                                                                       \
    __builtin_amdgcn_s_setprio(0);                                          \
  } while (0)

#define ST_A_LO(dstw, koff) { async_copy16(gA[0] + (koff), (dstw));          \
                              async_copy16(gA[2] + (koff), (dstw) + 16384); }
#define ST_A_HI(dstw, koff) { async_copy16(gA[1] + (koff), (dstw) + 8192);   \
                              async_copy16(gA[3] + (koff), (dstw) + 24576); }
#define ST_B_LO(dstw, koff) { async_copy16(gB[0] + (koff), (dstw));          \
                              async_copy16(gB[1] + (koff), (dstw) + 8192); }
#define ST_B_HI(dstw, koff) { async_copy16(gB[2] + (koff), (dstw) + 16384);  \
                              async_copy16(gB[3] + (koff), (dstw) + 24576); }

template <bool RELU_BF16>
__global__ __launch_bounds__(512, 2)
void gemm_w8(const unsigned short* __restrict__ A,   // bf16 [M][K]
             const unsigned short* __restrict__ BT,  // bf16 [N][K]
             const float* __restrict__ bias,         // [N]
             void* __restrict__ Cout,                // bf16 or f32 [M][N]
             int M, int N, int K, int nbn_shift) {
  extern __shared__ char lds[];
  const char* aE = lds;
  const char* aO = lds + 32768;
  const char* bE = lds + 65536;
  const char* bO = lds + 98304;

  const int tid = threadIdx.x;
  const int wave = tid >> 6, lane = tid & 63;
  const int wr = wave >> 2, wc = wave & 3;

  char* aEw = (char*)aE + wave * 1024;
  char* aOw = (char*)aO + wave * 1024;
  char* bEw = (char*)bE + wave * 1024;
  char* bOw = (char*)bO + wave * 1024;

  const int nwg = gridDim.x;
  const int wg = blockIdx.x;
  const int swz = (wg & 7) * (nwg >> 3) + (wg >> 3);
  const int bm = swz >> nbn_shift;
  const int bn = swz & ((1 << nbn_shift) - 1);
  const int m0 = bm << 8, n0 = bn << 8;

  const int srow = tid >> 3;
  const int sk = ((tid & 7) ^ (srow & 7)) << 3;
  const unsigned short* gA[4];
  const unsigned short* gB[4];
#pragma unroll
  for (int c = 0; c < 4; ++c) {
    gA[c] = A + (size_t)(m0 + c * 64 + srow) * K + sk;
    gB[c] = BT + (size_t)(n0 + c * 64 + srow) * K + sk;
  }

  const int lr = lane & 15, lg = lane >> 4;
  const int c0 = ((lg ^ (lr & 7)) << 4);
  const int abase = (wr * 128 + lr) * 128;
  const int bbase = (wc * 64 + lr) * 128;

  f32x4 acc[8][4] = {};
  bf16x8 af[4][2], b01[2][2], b23[2][2];

  ST_B_LO(bEw, 0);  ST_B_HI(bEw, 0);
  ST_A_LO(aEw, 0);  ST_A_HI(aEw, 0);
  ST_B_LO(bOw, 64); ST_B_HI(bOw, 64);
  VMW(4);
  BAR();

  const int NT = K >> 6;

  for (int it = 0; it < (NT - 2) / 2; ++it) {
    const int kE = (2 * it) << 6;
    RD_B(b01, bE, 0); RD_A(af, aE, 0); RD_B(b23, bE, 2);
    ST_A_LO(aOw, kE + 64); ST_A_HI(aOw, kE + 64);
    QUAD(0, 0, af, b01); QUAD(0, 2, af, b23);
    BAR();
    RD_A(af, aE, 4);
    ST_B_LO(bEw, kE + 128); ST_B_HI(bEw, kE + 128);
    QUAD(4, 2, af, b23); QUAD(4, 0, af, b01);
    VMW(4); BAR();
    RD_B(b01, bO, 0); RD_A(af, aO, 0); RD_B(b23, bO, 2);
    ST_A_LO(aEw, kE + 128); ST_A_HI(aEw, kE + 128);
    QUAD(0, 0, af, b01); QUAD(0, 2, af, b23);
    BAR();
    RD_A(af, aO, 4);
    ST_B_LO(bOw, kE + 192); ST_B_HI(bOw, kE + 192);
    QUAD(4, 2, af, b23); QUAD(4, 0, af, b01);
    VMW(4); BAR();
  }
  {
    const int kL = (NT - 1) << 6;
    RD_B(b01, bE, 0); RD_A(af, aE, 0); RD_B(b23, bE, 2);
    ST_A_LO(aOw, kL); ST_A_HI(aOw, kL);
    QUAD(0, 0, af, b01); QUAD(0, 2, af, b23);
    BAR();
    RD_A(af, aE, 4);
    QUAD(4, 2, af, b23); QUAD(4, 0, af, b01);
    VMW(0); BAR();
    RD_B(b01, bO, 0); RD_A(af, aO, 0); RD_B(b23, bO, 2);
    QUAD(0, 0, af, b01); QUAD(0, 2, af, b23);
    BAR();
    RD_A(af, aO, 4);
    QUAD(4, 2, af, b23); QUAD(4, 0, af, b01);
  }

  const int ccol = n0 + wc * 64;
  const int crow = m0 + wr * 128;
  float bv[4];
#pragma unroll
  for (int n = 0; n < 4; ++n) bv[n] = bias[ccol + n * 16 + lr];

  if (RELU_BF16) {
    unsigned short* O = (unsigned short*)Cout;
#pragma unroll
    for (int m = 0; m < 8; ++m)
#pragma unroll
      for (int j = 0; j < 4; ++j) {
        size_t r = (size_t)(crow + m * 16 + lg * 4 + j) * N;
#pragma unroll
        for (int n = 0; n < 4; ++n) {
          float v = acc[m][n][j] + bv[n];
          O[r + ccol + n * 16 + lr] = f2bf(fmaxf(v, 0.0f));
        }
      }
  } else {
    float* O = (float*)Cout;
#pragma unroll
    for (int m = 0; m < 8; ++m)
#pragma unroll
      for (int j = 0; j < 4; ++j) {
        size_t r = (size_t)(crow + m * 16 + lg * 4 + j) * N;
#pragma unroll
        for (int n = 0; n < 4; ++n)
          O[r + ccol + n * 16 + lr] = acc[m][n][j] + bv[n];
      }
  }
}

// ================= Kernel B: 4-wave ILP GEMM (GEMM2) ======================
// 256x256 tile, BK=64, 4 waves (2x2), per-wave 128x128 out, mfma 32x32x16.
// LDS [256][64] bf16 per operand, chunk swizzle f(r) = (r&7) ^ ((r>>3)&3).
// Round-8 verbatim (80us on GEMM2).

#define ILDA(base, m, ks) \
  (*(const bf16x8*)((base) + i_abase + (m) * 4096 + (i_c0 ^ ((ks) << 5))))
#define ILDB(base, n, ks) \
  (*(const bf16x8*)((base) + i_bbase + (n) * 4096 + (i_c0 ^ ((ks) << 5))))

#define ICOMPUTE(aB, bB)                                                      \
  _Pragma("unroll") for (int ks = 0; ks < 4; ++ks) {                          \
    bf16x8 af[4], bfr[4];                                                     \
    _Pragma("unroll") for (int i = 0; i < 4; ++i) {                           \
      af[i] = ILDA(aB, i, ks);                                                \
      bfr[i] = ILDB(bB, i, ks);                                               \
    }                                                                         \
    _Pragma("unroll") for (int m_ = 0; m_ < 4; ++m_)                          \
    _Pragma("unroll") for (int n_ = 0; n_ < 4; ++n_)                          \
      acc[m_][n_] = __builtin_amdgcn_mfma_f32_32x32x16_bf16(                  \
          af[m_], bfr[n_], acc[m_][n_], 0, 0, 0);                             \
  }

#define ISTAGE(buf_, koff_)                                                   \
  _Pragma("unroll") for (int j = 0; j < 8; ++j) {                             \
    async_copy16(gAb + (size_t)j * 32 * K + (koff_),                          \
                 ldsAw + (buf_) * 32768 + j * 4096);                          \
    async_copy16(gBb + (size_t)j * 32 * K + (koff_),                          \
                 ldsBw + (buf_) * 32768 + j * 4096);                          \
  }

template <bool RELU_BF16>
__global__ __launch_bounds__(256, 1)
void gemm_ilp4(const unsigned short* __restrict__ A,   // bf16 [M][K]
               const unsigned short* __restrict__ BT,  // bf16 [N][K]
               const float* __restrict__ bias,         // [N]
               void* __restrict__ Cout,                // bf16 or f32 [M][N]
               int M, int N, int K, int nbn_shift) {
  extern __shared__ char lds[];
  char* ldsA = lds;             // [2][32768]
  char* ldsB = lds + 65536;     // [2][32768]

  const int tid = threadIdx.x;
  const int wave = tid >> 6, lane = tid & 63;
  const int wr = wave >> 1, wc = wave & 1;  // 2x2 waves, each 128x128 out

  const int nwg = gridDim.x;
  const int wg = blockIdx.x;
  const int swz = (wg & 7) * (nwg >> 3) + (wg >> 3);
  const int bm = swz >> nbn_shift;
  const int bn = swz & ((1 << nbn_shift) - 1);
  const int m0 = bm << 8, n0 = bn << 8;

  const int srow = lane >> 3;
  const int skb = (((lane & 7) ^ srow ^ wave) << 3);
  const unsigned short* gAb = A + (size_t)(m0 + wave * 8 + srow) * K + skb;
  const unsigned short* gBb = BT + (size_t)(n0 + wave * 8 + srow) * K + skb;
  char* ldsAw = ldsA + wave * 1024;
  char* ldsBw = ldsB + wave * 1024;

  const int cl31 = lane & 31, lg2 = lane >> 5;
  const int i_c0 = ((lg2 ^ (lane & 7) ^ ((lane >> 3) & 3)) << 4);
  const int i_abase = (wr * 128 + cl31) * 128;
  const int i_bbase = (wc * 128 + cl31) * 128;

  f32x16 acc[4][4] = {};

  ISTAGE(0, 0);
  ISTAGE(1, 64);
  VMW(16);
  BAR();

  const int NT = K >> 6;

  for (int t = 0; t < NT - 2; ++t) {
    const char* aB = ldsA + (t & 1) * 32768;
    const char* bB = ldsB + (t & 1) * 32768;
    ICOMPUTE(aB, bB);
    BAR();
    SCHEDB();
    ISTAGE(t & 1, (t + 2) << 6);
    VMW(16);
    BAR();
  }
  ICOMPUTE(ldsA, ldsB);
  BAR();
  VMW(0);
  BAR();
  ICOMPUTE((ldsA + 32768), (ldsB + 32768));

  // epilogue: 32x32 C/D: col = lane&31, row = (r&3) + 8*(r>>2) + 4*(l>>5)
  const int ccol = n0 + wc * 128;
  const int crow = m0 + wr * 128;
  float bv[4];
#pragma unroll
  for (int n = 0; n < 4; ++n) bv[n] = bias[ccol + n * 32 + cl31];

  if (RELU_BF16) {
    unsigned short* O = (unsigned short*)Cout;
#pragma unroll
    for (int m = 0; m < 4; ++m)
#pragma unroll
      for (int rr = 0; rr < 4; ++rr)
#pragma unroll
        for (int q = 0; q < 4; ++q) {
          size_t r = (size_t)(crow + m * 32 + lg2 * 4 + q + 8 * rr) * N;
#pragma unroll
          for (int n = 0; n < 4; ++n) {
            float v = acc[m][n][rr * 4 + q] + bv[n];
            O[r + ccol + n * 32 + cl31] = f2bf(fmaxf(v, 0.0f));
          }
        }
  } else {
    float* O = (float*)Cout;
#pragma unroll
    for (int m = 0; m < 4; ++m)
#pragma unroll
      for (int rr = 0; rr < 4; ++rr)
#pragma unroll
        for (int q = 0; q < 4; ++q) {
          size_t r = (size_t)(crow + m * 32 + lg2 * 4 + q + 8 * rr) * N;
#pragma unroll
          for (int n = 0; n < 4; ++n)
            O[r + ccol + n * 32 + cl31] = acc[m][n][rr * 4 + q] + bv[n];
        }
  }
}

// ---------------- launch ----------------

extern "C" void kernel_launch(void* const* d_in, const int* in_sizes, int n_in,
                              void* d_out, int out_size, void* d_ws,
                              size_t ws_size, hipStream_t stream) {
  const float* x  = (const float*)d_in[0];   // [16384,1024]
  const float* W1 = (const float*)d_in[1];   // [1024,4096]
  const float* b1 = (const float*)d_in[2];   // [4096]
  const float* W2 = (const float*)d_in[3];   // [4096,1024]
  const float* b2 = (const float*)d_in[4];   // [1024]
  float* out = (float*)d_out;                // [16384,1024] f32

  const int B = 16384, DIN = 1024, DH = 4096, DOUT = 1024;

  size_t need = (size_t)B * DIN * 2 + (size_t)DIN * DH * 2 +
                (size_t)DH * DOUT * 2 + (size_t)B * DH * 2;
  if (ws_size < need) return;

  char* ws = (char*)d_ws;
  unsigned short* xb  = (unsigned short*)ws;  ws += (size_t)B * DIN * 2;
  unsigned short* w1t = (unsigned short*)ws;  ws += (size_t)DIN * DH * 2;  // [DH][DIN]
  unsigned short* w2t = (unsigned short*)ws;  ws += (size_t)DH * DOUT * 2; // [DOUT][DH]
  unsigned short* h   = (unsigned short*)ws;                               // [B][DH]

  hipFuncSetAttribute((const void*)gemm_w8<true>,
                      hipFuncAttributeMaxDynamicSharedMemorySize, 131072);
  hipFuncSetAttribute((const void*)gemm_ilp4<false>,
                      hipFuncAttributeMaxDynamicSharedMemorySize, 131072);

  int n4 = B * DIN / 4;
  cvt_f32_bf16<<<n4 / 256, 256, 0, stream>>>((const float4*)x, (ushort4*)xb, n4);
  transpose_f32_bf16<<<dim3(DH / 32, DIN / 32), dim3(32, 8), 0, stream>>>(W1, w1t, DIN, DH);
  transpose_f32_bf16<<<dim3(DOUT / 32, DH / 32), dim3(32, 8), 0, stream>>>(W2, w2t, DH, DOUT);

  // h = relu(x @ W1 + b1) : M=16384, N=4096, K=1024 (NT=16), 1024 wgs, W8
  gemm_w8<true><<<dim3((B / 256) * (DH / 256)), 512, 131072, stream>>>(
      xb, w1t, b1, h, B, DH, DIN, 4);
  // out = h @ W2 + b2     : M=16384, N=1024, K=4096 (NT=64), 256 wgs, ILP4
  gemm_ilp4<false><<<dim3((B / 256) * (DOUT / 256)), 256, 131072, stream>>>(
      h, w2t, b2, out, B, DOUT, DH, 2);
}

// Round 11
// 292.806 us; speedup vs baseline: 1.4658x; 1.0049x over previous
//
#include <hip/hip_runtime.h>
#include <hip/hip_bf16.h>
#include <stdint.h>

// LimitRegressor = relu(x@W1+b1)@W2+b2 followed by a fixed-point iteration
// whose unique fixed point is y*=out (tanh contraction, global early-exit at
// eps=1e-6 fires at k~13 with residual < 3e-7 << the 6.09e-2 threshold).
// So we emit out directly: two bf16 MFMA GEMMs.
//
// Composition (round-11 ledger, totals-based):
//  - GEMM1 (K=1024, NT=16, 1024 wgs): 8-wave 2-phase kernel (R6 champion
//    component; best measured for the 4-round regime).
//  - GEMM2 (K=4096, NT=64, 256 wgs): 4-wave ILP kernel with REGISTER
//    DOUBLE-BUFFERED operands: MFMA blocks its wave, so single-set
//    {reads;MFMA} serializes LDS and matrix pipes per wave. Two static
//    operand sets interleaved {MFMA(A); READ(A,ks+2); MFMA(B); ...} put
//    8 reads in flight under every 16-MFMA burst. +32 VGPR (496<=512 at
//    1 wave/SIMD).

#define DEV __device__ __forceinline__

typedef short bf16x8 __attribute__((ext_vector_type(8)));
typedef float f32x4 __attribute__((ext_vector_type(4)));
typedef float f32x16 __attribute__((ext_vector_type(16)));

typedef __attribute__((address_space(1))) const unsigned char* gptr1_t;
typedef __attribute__((address_space(3))) unsigned char* lptr3_t;

DEV void async_copy16(const void* g, void* l) {
  __builtin_amdgcn_global_load_lds((gptr1_t)g, (lptr3_t)l, 16, 0, 0);
}

DEV unsigned short f2bf(float f) {
  union { float f; unsigned u; } v; v.f = f;
  unsigned u = v.u + 0x7FFFu + ((v.u >> 16) & 1u);  // RNE
  return (unsigned short)(u >> 16);
}

#define BAR()    __builtin_amdgcn_s_barrier()
#define VMW(n)   asm volatile("s_waitcnt vmcnt(" #n ")" ::: "memory")
#define SCHEDB() __builtin_amdgcn_sched_barrier(0)

// ---------------- prep kernels ----------------

__global__ void cvt_f32_bf16(const float4* __restrict__ in,
                             ushort4* __restrict__ out, int n4) {
  int i = blockIdx.x * blockDim.x + threadIdx.x;
  if (i >= n4) return;
  float4 v = in[i];
  ushort4 o;
  o.x = f2bf(v.x); o.y = f2bf(v.y); o.z = f2bf(v.z); o.w = f2bf(v.w);
  out[i] = o;
}

// f32 [R][C] row-major  ->  bf16 [C][R] row-major (W -> W^T as bf16)
__global__ void transpose_f32_bf16(const float* __restrict__ in,
                                   unsigned short* __restrict__ out,
                                   int R, int C) {
  __shared__ float tile[32][33];
  int c0 = blockIdx.x * 32, r0 = blockIdx.y * 32;
  int tx = threadIdx.x, ty = threadIdx.y;  // block (32, 8)
#pragma unroll
  for (int i = 0; i < 32; i += 8)
    tile[ty + i][tx] = in[(long)(r0 + ty + i) * C + (c0 + tx)];
  __syncthreads();
#pragma unroll
  for (int i = 0; i < 32; i += 8)
    out[(long)(c0 + ty + i) * R + (r0 + tx)] = f2bf(tile[tx][ty + i]);
}

// ================= Kernel A: 8-wave 2-phase GEMM (GEMM1) ==================
// 256x256 tile, BK=64, 8 waves (2Mx4N), mfma 16x16x32, dbuf 128KiB LDS,
// two phases/tile, counted VMW(4), chunk-XOR swizzle. Round-6 verbatim.

#define LDA(base, m, ks) \
  (*(const bf16x8*)((base) + abase + (m) * 2048 + (c0 ^ ((ks) << 6))))
#define LDB(base, n, ks) \
  (*(const bf16x8*)((base) + bbase + (n) * 2048 + (c0 ^ ((ks) << 6))))

#define RD_A(dst, base, m0_)                                   \
  _Pragma("unroll") for (int m_ = 0; m_ < 4; ++m_) {           \
    dst[m_][0] = LDA(base, (m0_) + m_, 0);                     \
    dst[m_][1] = LDA(base, (m0_) + m_, 1);                     \
  }
#define RD_B(dst, base, n0_)                                   \
  _Pragma("unroll") for (int n_ = 0; n_ < 2; ++n_) {           \
    dst[n_][0] = LDB(base, (n0_) + n_, 0);                     \
    dst[n_][1] = LDB(base, (n0_) + n_, 1);                     \
  }

#define QUAD(MB, NB, AF, BF)                                                \
  do {                                                                      \
    __builtin_amdgcn_s_setprio(1);                                          \
    _Pragma("unroll") for (int m_ = 0; m_ < 4; ++m_)                        \
    _Pragma("unroll") for (int n_ = 0; n_ < 2; ++n_) {                      \
      acc[(MB) + m_][(NB) + n_] = __builtin_amdgcn_mfma_f32_16x16x32_bf16(  \
          AF[m_][0], BF[n_][0], acc[(MB) + m_][(NB) + n_], 0, 0, 0);        \
      acc[(MB) + m_][(NB) + n_] = __builtin_amdgcn_mfma_f32_16x16x32_bf16(  \
          AF[m_][1], BF[n_][1], acc[(MB) + m_][(NB) + n_], 0, 0, 0);        \
    }                                                                       \
    __builtin_amdgcn_s_setprio(0);                                          \
  } while (0)

#define ST_A_LO(dstw, koff) { async_copy16(gA[0] + (koff), (dstw));          \
                              async_copy16(gA[2] + (koff), (dstw) + 16384); }
#define ST_A_HI(dstw, koff) { async_copy16(gA[1] + (koff), (dstw) + 8192);   \
                              async_copy16(gA[3] + (koff), (dstw) + 24576); }
#define ST_B_LO(dstw, koff) { async_copy16(gB[0] + (koff), (dstw));          \
                              async_copy16(gB[1] + (koff), (dstw) + 8192); }
#define ST_B_HI(dstw, koff) { async_copy16(gB[2] + (koff), (dstw) + 16384);  \
                              async_copy16(gB[3] + (koff), (dstw) + 24576); }

template <bool RELU_BF16>
__global__ __launch_bounds__(512, 2)
void gemm_w8(const unsigned short* __restrict__ A,   // bf16 [M][K]
             const unsigned short* __restrict__ BT,  // bf16 [N][K]
             const float* __restrict__ bias,         // [N]
             void* __restrict__ Cout,                // bf16 or f32 [M][N]
             int M, int N, int K, int nbn_shift) {
  extern __shared__ char lds[];
  const char* aE = lds;
  const char* aO = lds + 32768;
  const char* bE = lds + 65536;
  const char* bO = lds + 98304;

  const int tid = threadIdx.x;
  const int wave = tid >> 6, lane = tid & 63;
  const int wr = wave >> 2, wc = wave & 3;

  char* aEw = (char*)aE + wave * 1024;
  char* aOw = (char*)aO + wave * 1024;
  char* bEw = (char*)bE + wave * 1024;
  char* bOw = (char*)bO + wave * 1024;

  const int nwg = gridDim.x;
  const int wg = blockIdx.x;
  const int swz = (wg & 7) * (nwg >> 3) + (wg >> 3);
  const int bm = swz >> nbn_shift;
  const int bn = swz & ((1 << nbn_shift) - 1);
  const int m0 = bm << 8, n0 = bn << 8;

  const int srow = tid >> 3;
  const int sk = ((tid & 7) ^ (srow & 7)) << 3;
  const unsigned short* gA[4];
  const unsigned short* gB[4];
#pragma unroll
  for (int c = 0; c < 4; ++c) {
    gA[c] = A + (size_t)(m0 + c * 64 + srow) * K + sk;
    gB[c] = BT + (size_t)(n0 + c * 64 + srow) * K + sk;
  }

  const int lr = lane & 15, lg = lane >> 4;
  const int c0 = ((lg ^ (lr & 7)) << 4);
  const int abase = (wr * 128 + lr) * 128;
  const int bbase = (wc * 64 + lr) * 128;

  f32x4 acc[8][4] = {};
  bf16x8 af[4][2], b01[2][2], b23[2][2];

  ST_B_LO(bEw, 0);  ST_B_HI(bEw, 0);
  ST_A_LO(aEw, 0);  ST_A_HI(aEw, 0);
  ST_B_LO(bOw, 64); ST_B_HI(bOw, 64);
  VMW(4);
  BAR();

  const int NT = K >> 6;

  for (int it = 0; it < (NT - 2) / 2; ++it) {
    const int kE = (2 * it) << 6;
    RD_B(b01, bE, 0); RD_A(af, aE, 0); RD_B(b23, bE, 2);
    ST_A_LO(aOw, kE + 64); ST_A_HI(aOw, kE + 64);
    QUAD(0, 0, af, b01); QUAD(0, 2, af, b23);
    BAR();
    RD_A(af, aE, 4);
    ST_B_LO(bEw, kE + 128); ST_B_HI(bEw, kE + 128);
    QUAD(4, 2, af, b23); QUAD(4, 0, af, b01);
    VMW(4); BAR();
    RD_B(b01, bO, 0); RD_A(af, aO, 0); RD_B(b23, bO, 2);
    ST_A_LO(aEw, kE + 128); ST_A_HI(aEw, kE + 128);
    QUAD(0, 0, af, b01); QUAD(0, 2, af, b23);
    BAR();
    RD_A(af, aO, 4);
    ST_B_LO(bOw, kE + 192); ST_B_HI(bOw, kE + 192);
    QUAD(4, 2, af, b23); QUAD(4, 0, af, b01);
    VMW(4); BAR();
  }
  {
    const int kL = (NT - 1) << 6;
    RD_B(b01, bE, 0); RD_A(af, aE, 0); RD_B(b23, bE, 2);
    ST_A_LO(aOw, kL); ST_A_HI(aOw, kL);
    QUAD(0, 0, af, b01); QUAD(0, 2, af, b23);
    BAR();
    RD_A(af, aE, 4);
    QUAD(4, 2, af, b23); QUAD(4, 0, af, b01);
    VMW(0); BAR();
    RD_B(b01, bO, 0); RD_A(af, aO, 0); RD_B(b23, bO, 2);
    QUAD(0, 0, af, b01); QUAD(0, 2, af, b23);
    BAR();
    RD_A(af, aO, 4);
    QUAD(4, 2, af, b23); QUAD(4, 0, af, b01);
  }

  const int ccol = n0 + wc * 64;
  const int crow = m0 + wr * 128;
  float bv[4];
#pragma unroll
  for (int n = 0; n < 4; ++n) bv[n] = bias[ccol + n * 16 + lr];

  if (RELU_BF16) {
    unsigned short* O = (unsigned short*)Cout;
#pragma unroll
    for (int m = 0; m < 8; ++m)
#pragma unroll
      for (int j = 0; j < 4; ++j) {
        size_t r = (size_t)(crow + m * 16 + lg * 4 + j) * N;
#pragma unroll
        for (int n = 0; n < 4; ++n) {
          float v = acc[m][n][j] + bv[n];
          O[r + ccol + n * 16 + lr] = f2bf(fmaxf(v, 0.0f));
        }
      }
  } else {
    float* O = (float*)Cout;
#pragma unroll
    for (int m = 0; m < 8; ++m)
#pragma unroll
      for (int j = 0; j < 4; ++j) {
        size_t r = (size_t)(crow + m * 16 + lg * 4 + j) * N;
#pragma unroll
        for (int n = 0; n < 4; ++n)
          O[r + ccol + n * 16 + lr] = acc[m][n][j] + bv[n];
      }
  }
}

// ========= Kernel B: 4-wave ILP GEMM, reg-double-buffered (GEMM2) =========
// 256x256 tile, BK=64, 4 waves (2x2), per-wave 128x128 out, mfma 32x32x16.
// LDS [256][64] bf16 per operand, chunk swizzle f(r) = (r&7) ^ ((r>>3)&3).
// Two static operand sets (afA/bfA, afB/bfB): every 16-MFMA burst covers
// the other set's 8 ds_read_b128 in flight (MFMA blocks its wave, so a
// single set serializes LDS and matrix pipes).

#define ILDA(base, m, ks) \
  (*(const bf16x8*)((base) + i_abase + (m) * 4096 + (i_c0 ^ ((ks) << 5))))
#define ILDB(base, n, ks) \
  (*(const bf16x8*)((base) + i_bbase + (n) * 4096 + (i_c0 ^ ((ks) << 5))))

#define IREAD(AF, BF, aB, bB, ks)                                             \
  _Pragma("unroll") for (int i = 0; i < 4; ++i) {                             \
    AF[i] = ILDA(aB, i, ks);                                                  \
    BF[i] = ILDB(bB, i, ks);                                                  \
  }

#define IMFMA(AF, BF)                                                         \
  _Pragma("unroll") for (int m_ = 0; m_ < 4; ++m_)                            \
  _Pragma("unroll") for (int n_ = 0; n_ < 4; ++n_)                            \
    acc[m_][n_] = __builtin_amdgcn_mfma_f32_32x32x16_bf16(                    \
        AF[m_], BF[n_], acc[m_][n_], 0, 0, 0);

// pipelined K-tile: reads of set X issued between the two other MFMA bursts
#define ICOMPUTE_PIPE(aB, bB)                                                 \
  {                                                                           \
    IREAD(afA, bfA, aB, bB, 0);                                               \
    IREAD(afB, bfB, aB, bB, 1);                                               \
    IMFMA(afA, bfA);                                                          \
    IREAD(afA, bfA, aB, bB, 2);                                               \
    IMFMA(afB, bfB);                                                          \
    IREAD(afB, bfB, aB, bB, 3);                                               \
    IMFMA(afA, bfA);                                                          \
    IMFMA(afB, bfB);                                                          \
  }

#define ISTAGE(buf_, koff_)                                                   \
  _Pragma("unroll") for (int j = 0; j < 8; ++j) {                             \
    async_copy16(gAb + (size_t)j * 32 * K + (koff_),                          \
                 ldsAw + (buf_) * 32768 + j * 4096);                          \
    async_copy16(gBb + (size_t)j * 32 * K + (koff_),                          \
                 ldsBw + (buf_) * 32768 + j * 4096);                          \
  }

template <bool RELU_BF16>
__global__ __launch_bounds__(256, 1)
void gemm_ilp4(const unsigned short* __restrict__ A,   // bf16 [M][K]
               const unsigned short* __restrict__ BT,  // bf16 [N][K]
               const float* __restrict__ bias,         // [N]
               void* __restrict__ Cout,                // bf16 or f32 [M][N]
               int M, int N, int K, int nbn_shift) {
  extern __shared__ char lds[];
  char* ldsA = lds;             // [2][32768]
  char* ldsB = lds + 65536;     // [2][32768]

  const int tid = threadIdx.x;
  const int wave = tid >> 6, lane = tid & 63;
  const int wr = wave >> 1, wc = wave & 1;  // 2x2 waves, each 128x128 out

  const int nwg = gridDim.x;
  const int wg = blockIdx.x;
  const int swz = (wg & 7) * (nwg >> 3) + (wg >> 3);
  const int bm = swz >> nbn_shift;
  const int bn = swz & ((1 << nbn_shift) - 1);
  const int m0 = bm << 8, n0 = bn << 8;

  const int srow = lane >> 3;
  const int skb = (((lane & 7) ^ srow ^ wave) << 3);
  const unsigned short* gAb = A + (size_t)(m0 + wave * 8 + srow) * K + skb;
  const unsigned short* gBb = BT + (size_t)(n0 + wave * 8 + srow) * K + skb;
  char* ldsAw = ldsA + wave * 1024;
  char* ldsBw = ldsB + wave * 1024;

  const int cl31 = lane & 31, lg2 = lane >> 5;
  const int i_c0 = ((lg2 ^ (lane & 7) ^ ((lane >> 3) & 3)) << 4);
  const int i_abase = (wr * 128 + cl31) * 128;
  const int i_bbase = (wc * 128 + cl31) * 128;

  f32x16 acc[4][4] = {};
  bf16x8 afA[4], bfA[4], afB[4], bfB[4];  // two static operand sets

  ISTAGE(0, 0);
  ISTAGE(1, 64);
  VMW(16);
  BAR();

  const int NT = K >> 6;

  for (int t = 0; t < NT - 2; ++t) {
    const char* aB = ldsA + (t & 1) * 32768;
    const char* bB = ldsB + (t & 1) * 32768;
    ICOMPUTE_PIPE(aB, bB);
    BAR();
    SCHEDB();
    ISTAGE(t & 1, (t + 2) << 6);
    VMW(16);
    BAR();
  }
  ICOMPUTE_PIPE(ldsA, ldsB);
  BAR();
  VMW(0);
  BAR();
  ICOMPUTE_PIPE((ldsA + 32768), (ldsB + 32768));

  // epilogue: 32x32 C/D: col = lane&31, row = (r&3) + 8*(r>>2) + 4*(l>>5)
  const int ccol = n0 + wc * 128;
  const int crow = m0 + wr * 128;
  float bv[4];
#pragma unroll
  for (int n = 0; n < 4; ++n) bv[n] = bias[ccol + n * 32 + cl31];

  if (RELU_BF16) {
    unsigned short* O = (unsigned short*)Cout;
#pragma unroll
    for (int m = 0; m < 4; ++m)
#pragma unroll
      for (int rr = 0; rr < 4; ++rr)
#pragma unroll
        for (int q = 0; q < 4; ++q) {
          size_t r = (size_t)(crow + m * 32 + lg2 * 4 + q + 8 * rr) * N;
#pragma unroll
          for (int n = 0; n < 4; ++n) {
            float v = acc[m][n][rr * 4 + q] + bv[n];
            O[r + ccol + n * 32 + cl31] = f2bf(fmaxf(v, 0.0f));
          }
        }
  } else {
    float* O = (float*)Cout;
#pragma unroll
    for (int m = 0; m < 4; ++m)
#pragma unroll
      for (int rr = 0; rr < 4; ++rr)
#pragma unroll
        for (int q = 0; q < 4; ++q) {
          size_t r = (size_t)(crow + m * 32 + lg2 * 4 + q + 8 * rr) * N;
#pragma unroll
          for (int n = 0; n < 4; ++n)
            O[r + ccol + n * 32 + cl31] = acc[m][n][rr * 4 + q] + bv[n];
        }
  }
}

// ---------------- launch ----------------

extern "C" void kernel_launch(void* const* d_in, const int* in_sizes, int n_in,
                              void* d_out, int out_size, void* d_ws,
                              size_t ws_size, hipStream_t stream) {
  const float* x  = (const float*)d_in[0];   // [16384,1024]
  const float* W1 = (const float*)d_in[1];   // [1024,4096]
  const float* b1 = (const float*)d_in[2];   // [4096]
  const float* W2 = (const float*)d_in[3];   // [4096,1024]
  const float* b2 = (const float*)d_in[4];   // [1024]
  float* out = (float*)d_out;                // [16384,1024] f32

  const int B = 16384, DIN = 1024, DH = 4096, DOUT = 1024;

  size_t need = (size_t)B * DIN * 2 + (size_t)DIN * DH * 2 +
                (size_t)DH * DOUT * 2 + (size_t)B * DH * 2;
  if (ws_size < need) return;

  char* ws = (char*)d_ws;
  unsigned short* xb  = (unsigned short*)ws;  ws += (size_t)B * DIN * 2;
  unsigned short* w1t = (unsigned short*)ws;  ws += (size_t)DIN * DH * 2;  // [DH][DIN]
  unsigned short* w2t = (unsigned short*)ws;  ws += (size_t)DH * DOUT * 2; // [DOUT][DH]
  unsigned short* h   = (unsigned short*)ws;                               // [B][DH]

  hipFuncSetAttribute((const void*)gemm_w8<true>,
                      hipFuncAttributeMaxDynamicSharedMemorySize, 131072);
  hipFuncSetAttribute((const void*)gemm_ilp4<false>,
                      hipFuncAttributeMaxDynamicSharedMemorySize, 131072);

  int n4 = B * DIN / 4;
  cvt_f32_bf16<<<n4 / 256, 256, 0, stream>>>((const float4*)x, (ushort4*)xb, n4);
  transpose_f32_bf16<<<dim3(DH / 32, DIN / 32), dim3(32, 8), 0, stream>>>(W1, w1t, DIN, DH);
  transpose_f32_bf16<<<dim3(DOUT / 32, DH / 32), dim3(32, 8), 0, stream>>>(W2, w2t, DH, DOUT);

  // h = relu(x @ W1 + b1) : M=16384, N=4096, K=1024 (NT=16), 1024 wgs, W8
  gemm_w8<true><<<dim3((B / 256) * (DH / 256)), 512, 131072, stream>>>(
      xb, w1t, b1, h, B, DH, DIN, 4);
  // out = h @ W2 + b2     : M=16384, N=1024, K=4096 (NT=64), 256 wgs, ILP4-pipe
  gemm_ilp4<false><<<dim3((B / 256) * (DOUT / 256)), 256, 131072, stream>>>(
      h, w2t, b2, out, B, DOUT, DH, 2);
}

// Round 12
// 272.708 us; speedup vs baseline: 1.5738x; 1.0737x over previous
//
#include <hip/hip_runtime.h>
#include <hip/hip_bf16.h>
#include <stdint.h>

// LimitRegressor = relu(x@W1+b1)@W2+b2 followed by a fixed-point iteration
// whose unique fixed point is y*=out (tanh contraction, global early-exit at
// eps=1e-6 fires at k~13 with residual < 3e-7 << the 6.09e-2 threshold).
// So we emit out directly: two bf16 MFMA GEMMs, both on the w8 2-phase
// structure (256x256 tile, BK=64, 8 waves 2Mx4N, mfma 16x16x32, dbuf 128KiB
// LDS, counted VMW(4), chunk-XOR swizzle, setprio). Totals-ledger (R11):
// steady state = 1.27us/tile (~1700 TF) but each launch-round costs ~17.5us
// (prologue fill + drain + straggler tail). G2 (1 round) hits 1395 TF; G1
// (4 rounds) only 910. Fix: PERSISTENT G1 - grid 256 (1/CU), fixed bn
// (B-panel L2-hot), one continuous 64-tile pipeline across 4 M-panels,
// acc flushed at 16-tile boundaries AFTER the VMW(4);BAR certification
// point (stores retire long before the next counted wait). w8's 128-AGPR
// acc + boundary-dead operand regs leave allocator slack (R9's ilp4
// persistent spilled at 256 AGPR).

#define DEV __device__ __forceinline__

typedef short bf16x8 __attribute__((ext_vector_type(8)));
typedef float f32x4 __attribute__((ext_vector_type(4)));

typedef __attribute__((address_space(1))) const unsigned char* gptr1_t;
typedef __attribute__((address_space(3))) unsigned char* lptr3_t;

DEV void async_copy16(const void* g, void* l) {
  __builtin_amdgcn_global_load_lds((gptr1_t)g, (lptr3_t)l, 16, 0, 0);
}

DEV unsigned short f2bf(float f) {
  union { float f; unsigned u; } v; v.f = f;
  unsigned u = v.u + 0x7FFFu + ((v.u >> 16) & 1u);  // RNE
  return (unsigned short)(u >> 16);
}

#define BAR()  __builtin_amdgcn_s_barrier()
#define VMW(n) asm volatile("s_waitcnt vmcnt(" #n ")" ::: "memory")

// ---------------- prep kernels ----------------

__global__ void cvt_f32_bf16(const float4* __restrict__ in,
                             ushort4* __restrict__ out, int n4) {
  int i = blockIdx.x * blockDim.x + threadIdx.x;
  if (i >= n4) return;
  float4 v = in[i];
  ushort4 o;
  o.x = f2bf(v.x); o.y = f2bf(v.y); o.z = f2bf(v.z); o.w = f2bf(v.w);
  out[i] = o;
}

// f32 [R][C] row-major  ->  bf16 [C][R] row-major (W -> W^T as bf16)
__global__ void transpose_f32_bf16(const float* __restrict__ in,
                                   unsigned short* __restrict__ out,
                                   int R, int C) {
  __shared__ float tile[32][33];
  int c0 = blockIdx.x * 32, r0 = blockIdx.y * 32;
  int tx = threadIdx.x, ty = threadIdx.y;  // block (32, 8)
#pragma unroll
  for (int i = 0; i < 32; i += 8)
    tile[ty + i][tx] = in[(long)(r0 + ty + i) * C + (c0 + tx)];
  __syncthreads();
#pragma unroll
  for (int i = 0; i < 32; i += 8)
    out[(long)(c0 + ty + i) * R + (r0 + tx)] = f2bf(tile[tx][ty + i]);
}

// ---------------- shared w8 building blocks ----------------
// LDS per operand per buf: 4 chunks of 8KB; chunk c = rows [c*64,c*64+64) x
// k[0,64) bf16, 16B-chunk XOR swizzle: LDS[row][c16] = global k-chunk
// (c16 ^ (row&7)). Staged with pre-swizzled global source (both-sides rule).

#define LDA(base, m, ks) \
  (*(const bf16x8*)((base) + abase + (m) * 2048 + (c0 ^ ((ks) << 6))))
#define LDB(base, n, ks) \
  (*(const bf16x8*)((base) + bbase + (n) * 2048 + (c0 ^ ((ks) << 6))))

#define RD_A(dst, base, m0_)                                   \
  _Pragma("unroll") for (int m_ = 0; m_ < 4; ++m_) {           \
    dst[m_][0] = LDA(base, (m0_) + m_, 0);                     \
    dst[m_][1] = LDA(base, (m0_) + m_, 1);                     \
  }
#define RD_B(dst, base, n0_)                                   \
  _Pragma("unroll") for (int n_ = 0; n_ < 2; ++n_) {           \
    dst[n_][0] = LDB(base, (n0_) + n_, 0);                     \
    dst[n_][1] = LDB(base, (n0_) + n_, 1);                     \
  }

#define QUAD(MB, NB, AF, BF)                                                \
  do {                                                                      \
    __builtin_amdgcn_s_setprio(1);                                          \
    _Pragma("unroll") for (int m_ = 0; m_ < 4; ++m_)                        \
    _Pragma("unroll") for (int n_ = 0; n_ < 2; ++n_) {                      \
      acc[(MB) + m_][(NB) + n_] = __builtin_amdgcn_mfma_f32_16x16x32_bf16(  \
          AF[m_][0], BF[n_][0], acc[(MB) + m_][(NB) + n_], 0, 0, 0);        \
      acc[(MB) + m_][(NB) + n_] = __builtin_amdgcn_mfma_f32_16x16x32_bf16(  \
          AF[m_][1], BF[n_][1], acc[(MB) + m_][(NB) + n_], 0, 0, 0);        \
    }                                                                       \
    __builtin_amdgcn_s_setprio(0);                                          \
  } while (0)

#define ST_A_LO(dstw, koff) { async_copy16(gA[0] + (koff), (dstw));          \
                              async_copy16(gA[2] + (koff), (dstw) + 16384); }
#define ST_A_HI(dstw, koff) { async_copy16(gA[1] + (koff), (dstw) + 8192);   \
                              async_copy16(gA[3] + (koff), (dstw) + 24576); }
#define ST_B_LO(dstw, koff) { async_copy16(gB[0] + (koff), (dstw));          \
                              async_copy16(gB[1] + (koff), (dstw) + 8192); }
#define ST_B_HI(dstw, koff) { async_copy16(gB[2] + (koff), (dstw) + 16384);  \
                              async_copy16(gB[3] + (koff), (dstw) + 24576); }

// ============ Kernel A: persistent w8 2-phase (GEMM1, K=1024) =============
// Grid 256. wg owns bn (16 values) and grp (16); loops 4 M-panels x 16
// K-tiles = 64 global tiles g through ONE pipeline. Flush at g%16==15.

__global__ __launch_bounds__(512, 2)
void gemm_w8p(const unsigned short* __restrict__ A,   // bf16 [16384][K]
              const unsigned short* __restrict__ BT,  // bf16 [Ndim][K]
              const float* __restrict__ bias,         // [Ndim]
              unsigned short* __restrict__ O,         // bf16 [16384][Ndim]
              int K, int Ndim) {                      // 1024, 4096
  extern __shared__ char lds[];
  const char* aE = lds;
  const char* aO = lds + 32768;
  const char* bE = lds + 65536;
  const char* bO = lds + 98304;

  const int tid = threadIdx.x;
  const int wave = tid >> 6, lane = tid & 63;
  const int wr = wave >> 2, wc = wave & 3;

  char* aEw = (char*)aE + wave * 1024;
  char* aOw = (char*)aO + wave * 1024;
  char* bEw = (char*)bE + wave * 1024;
  char* bOw = (char*)bO + wave * 1024;

  const int nwg = gridDim.x;              // 256
  const int wg = blockIdx.x;
  const int swz = (wg & 7) * (nwg >> 3) + (wg >> 3);
  const int bn = swz & 15;
  const int grp = swz >> 4;
  const int n0 = bn << 8;
  const int m0base = grp << 10;           // 4 M-panels of 256 rows

  const int srow = tid >> 3;
  const int sk = ((tid & 7) ^ (srow & 7)) << 3;
  const unsigned short* gA[4];
  const unsigned short* gB[4];
#pragma unroll
  for (int c = 0; c < 4; ++c) {
    gA[c] = A + (size_t)(m0base + c * 64 + srow) * K + sk;
    gB[c] = BT + (size_t)(n0 + c * 64 + srow) * K + sk;
  }

  const int lr = lane & 15, lg = lane >> 4;
  const int c0 = ((lg ^ (lr & 7)) << 4);
  const int abase = (wr * 128 + lr) * 128;
  const int bbase = (wc * 64 + lr) * 128;
  const int ccol = n0 + wc * 64;

  f32x4 acc[8][4] = {};
  bf16x8 af[4][2], b01[2][2], b23[2][2];
  float bv[4];
#pragma unroll
  for (int n = 0; n < 4; ++n) bv[n] = bias[ccol + n * 16 + lr];

  // global-tile offsets: tile g -> M-panel g>>4 (A rows +256 each), K-tile g&15
#define AOFF(g) ((size_t)((g) >> 4) * ((size_t)K << 8) + (size_t)(((g) & 15) << 6))
#define BOFF(g) ((size_t)(((g) & 15) << 6))

#define PEPI(j_)                                                              \
  { const int crow = m0base + (j_) * 256 + wr * 128;                          \
    _Pragma("unroll") for (int m = 0; m < 8; ++m)                             \
    _Pragma("unroll") for (int jj = 0; jj < 4; ++jj) {                        \
      size_t r = (size_t)(crow + m * 16 + lg * 4 + jj) * Ndim;                \
      _Pragma("unroll") for (int n = 0; n < 4; ++n) {                         \
        float v = acc[m][n][jj] + bv[n];                                      \
        O[r + ccol + n * 16 + lr] = f2bf(fmaxf(v, 0.0f));                     \
      } } }

#define ZEROACC()                                                             \
  _Pragma("unroll") for (int m = 0; m < 8; ++m)                               \
  _Pragma("unroll") for (int n = 0; n < 4; ++n)                               \
    acc[m][n] = (f32x4){0.f, 0.f, 0.f, 0.f};

  // prologue: B(0), A(0), B(1); certify B(0)+A(0), leave B(1) in flight
  ST_B_LO(bEw, 0);        ST_B_HI(bEw, 0);
  ST_A_LO(aEw, 0);        ST_A_HI(aEw, 0);
  ST_B_LO(bOw, BOFF(1));  ST_B_HI(bOw, BOFF(1));
  VMW(4);
  BAR();

  // 64 global tiles; iterate pairs (E=2it, O=2it+1), peel last pair.
  for (int it = 0; it < 31; ++it) {
    const int gE = 2 * it, gO = 2 * it + 1;
    // ---- tile E (even: read aE,bE; stage A(E+1)->aO, B(E+2)->bE) ----
    RD_B(b01, bE, 0); RD_A(af, aE, 0); RD_B(b23, bE, 2);
    ST_A_LO(aOw, AOFF(gE + 1)); ST_A_HI(aOw, AOFF(gE + 1));
    QUAD(0, 0, af, b01); QUAD(0, 2, af, b23);
    BAR();
    RD_A(af, aE, 4);
    ST_B_LO(bEw, BOFF(gE + 2)); ST_B_HI(bEw, BOFF(gE + 2));
    QUAD(4, 2, af, b23); QUAD(4, 0, af, b01);
    VMW(4); BAR();
    // ---- tile O (odd: read aO,bO; stage A(O+1)->aE, B(O+2)->bO) ----
    RD_B(b01, bO, 0); RD_A(af, aO, 0); RD_B(b23, bO, 2);
    ST_A_LO(aEw, AOFF(gO + 1)); ST_A_HI(aEw, AOFF(gO + 1));
    QUAD(0, 0, af, b01); QUAD(0, 2, af, b23);
    BAR();
    RD_A(af, aO, 4);
    ST_B_LO(bOw, BOFF(gO + 2)); ST_B_HI(bOw, BOFF(gO + 2));
    QUAD(4, 2, af, b23); QUAD(4, 0, af, b01);
    VMW(4); BAR();
    // ---- M-panel boundary (gO = 15, 31, 47): flush acc, stores drain in
    // background (next counted wait is ~25K cycles away) ----
    if ((it & 7) == 7) {
      PEPI(gO >> 4);
      ZEROACC();
    }
  }
  // ---- peel tiles 62, 63 ----
  RD_B(b01, bE, 0); RD_A(af, aE, 0); RD_B(b23, bE, 2);
  ST_A_LO(aOw, AOFF(63)); ST_A_HI(aOw, AOFF(63));
  QUAD(0, 0, af, b01); QUAD(0, 2, af, b23);
  BAR();
  RD_A(af, aE, 4);
  QUAD(4, 2, af, b23); QUAD(4, 0, af, b01);
  VMW(0); BAR();
  RD_B(b01, bO, 0); RD_A(af, aO, 0); RD_B(b23, bO, 2);
  QUAD(0, 0, af, b01); QUAD(0, 2, af, b23);
  BAR();
  RD_A(af, aO, 4);
  QUAD(4, 2, af, b23); QUAD(4, 0, af, b01);
  PEPI(3);
#undef PEPI
#undef ZEROACC
#undef AOFF
#undef BOFF
}

// ================= Kernel B: w8 2-phase GEMM (GEMM2) ======================
// Round-6 verbatim (98.5us = 1395 TF on GEMM2).

template <bool RELU_BF16>
__global__ __launch_bounds__(512, 2)
void gemm_w8(const unsigned short* __restrict__ A,   // bf16 [M][K]
             const unsigned short* __restrict__ BT,  // bf16 [N][K]
             const float* __restrict__ bias,         // [N]
             void* __restrict__ Cout,                // bf16 or f32 [M][N]
             int M, int N, int K, int nbn_shift) {
  extern __shared__ char lds[];
  const char* aE = lds;
  const char* aO = lds + 32768;
  const char* bE = lds + 65536;
  const char* bO = lds + 98304;

  const int tid = threadIdx.x;
  const int wave = tid >> 6, lane = tid & 63;
  const int wr = wave >> 2, wc = wave & 3;

  char* aEw = (char*)aE + wave * 1024;
  char* aOw = (char*)aO + wave * 1024;
  char* bEw = (char*)bE + wave * 1024;
  char* bOw = (char*)bO + wave * 1024;

  const int nwg = gridDim.x;
  const int wg = blockIdx.x;
  const int swz = (wg & 7) * (nwg >> 3) + (wg >> 3);
  const int bm = swz >> nbn_shift;
  const int bn = swz & ((1 << nbn_shift) - 1);
  const int m0 = bm << 8, n0 = bn << 8;

  const int srow = tid >> 3;
  const int sk = ((tid & 7) ^ (srow & 7)) << 3;
  const unsigned short* gA[4];
  const unsigned short* gB[4];
#pragma unroll
  for (int c = 0; c < 4; ++c) {
    gA[c] = A + (size_t)(m0 + c * 64 + srow) * K + sk;
    gB[c] = BT + (size_t)(n0 + c * 64 + srow) * K + sk;
  }

  const int lr = lane & 15, lg = lane >> 4;
  const int c0 = ((lg ^ (lr & 7)) << 4);
  const int abase = (wr * 128 + lr) * 128;
  const int bbase = (wc * 64 + lr) * 128;

  f32x4 acc[8][4] = {};
  bf16x8 af[4][2], b01[2][2], b23[2][2];

  ST_B_LO(bEw, 0);  ST_B_HI(bEw, 0);
  ST_A_LO(aEw, 0);  ST_A_HI(aEw, 0);
  ST_B_LO(bOw, 64); ST_B_HI(bOw, 64);
  VMW(4);
  BAR();

  const int NT = K >> 6;

  for (int it = 0; it < (NT - 2) / 2; ++it) {
    const int kE = (2 * it) << 6;
    RD_B(b01, bE, 0); RD_A(af, aE, 0); RD_B(b23, bE, 2);
    ST_A_LO(aOw, kE + 64); ST_A_HI(aOw, kE + 64);
    QUAD(0, 0, af, b01); QUAD(0, 2, af, b23);
    BAR();
    RD_A(af, aE, 4);
    ST_B_LO(bEw, kE + 128); ST_B_HI(bEw, kE + 128);
    QUAD(4, 2, af, b23); QUAD(4, 0, af, b01);
    VMW(4); BAR();
    RD_B(b01, bO, 0); RD_A(af, aO, 0); RD_B(b23, bO, 2);
    ST_A_LO(aEw, kE + 128); ST_A_HI(aEw, kE + 128);
    QUAD(0, 0, af, b01); QUAD(0, 2, af, b23);
    BAR();
    RD_A(af, aO, 4);
    ST_B_LO(bOw, kE + 192); ST_B_HI(bOw, kE + 192);
    QUAD(4, 2, af, b23); QUAD(4, 0, af, b01);
    VMW(4); BAR();
  }
  {
    const int kL = (NT - 1) << 6;
    RD_B(b01, bE, 0); RD_A(af, aE, 0); RD_B(b23, bE, 2);
    ST_A_LO(aOw, kL); ST_A_HI(aOw, kL);
    QUAD(0, 0, af, b01); QUAD(0, 2, af, b23);
    BAR();
    RD_A(af, aE, 4);
    QUAD(4, 2, af, b23); QUAD(4, 0, af, b01);
    VMW(0); BAR();
    RD_B(b01, bO, 0); RD_A(af, aO, 0); RD_B(b23, bO, 2);
    QUAD(0, 0, af, b01); QUAD(0, 2, af, b23);
    BAR();
    RD_A(af, aO, 4);
    QUAD(4, 2, af, b23); QUAD(4, 0, af, b01);
  }

  const int ccol = n0 + wc * 64;
  const int crow = m0 + wr * 128;
  float bv[4];
#pragma unroll
  for (int n = 0; n < 4; ++n) bv[n] = bias[ccol + n * 16 + lr];

  if (RELU_BF16) {
    unsigned short* O = (unsigned short*)Cout;
#pragma unroll
    for (int m = 0; m < 8; ++m)
#pragma unroll
      for (int j = 0; j < 4; ++j) {
        size_t r = (size_t)(crow + m * 16 + lg * 4 + j) * N;
#pragma unroll
        for (int n = 0; n < 4; ++n) {
          float v = acc[m][n][j] + bv[n];
          O[r + ccol + n * 16 + lr] = f2bf(fmaxf(v, 0.0f));
        }
      }
  } else {
    float* O = (float*)Cout;
#pragma unroll
    for (int m = 0; m < 8; ++m)
#pragma unroll
      for (int j = 0; j < 4; ++j) {
        size_t r = (size_t)(crow + m * 16 + lg * 4 + j) * N;
#pragma unroll
        for (int n = 0; n < 4; ++n)
          O[r + ccol + n * 16 + lr] = acc[m][n][j] + bv[n];
      }
  }
}

// ---------------- launch ----------------

extern "C" void kernel_launch(void* const* d_in, const int* in_sizes, int n_in,
                              void* d_out, int out_size, void* d_ws,
                              size_t ws_size, hipStream_t stream) {
  const float* x  = (const float*)d_in[0];   // [16384,1024]
  const float* W1 = (const float*)d_in[1];   // [1024,4096]
  const float* b1 = (const float*)d_in[2];   // [4096]
  const float* W2 = (const float*)d_in[3];   // [4096,1024]
  const float* b2 = (const float*)d_in[4];   // [1024]
  float* out = (float*)d_out;                // [16384,1024] f32

  const int B = 16384, DIN = 1024, DH = 4096, DOUT = 1024;

  size_t need = (size_t)B * DIN * 2 + (size_t)DIN * DH * 2 +
                (size_t)DH * DOUT * 2 + (size_t)B * DH * 2;
  if (ws_size < need) return;

  char* ws = (char*)d_ws;
  unsigned short* xb  = (unsigned short*)ws;  ws += (size_t)B * DIN * 2;
  unsigned short* w1t = (unsigned short*)ws;  ws += (size_t)DIN * DH * 2;  // [DH][DIN]
  unsigned short* w2t = (unsigned short*)ws;  ws += (size_t)DH * DOUT * 2; // [DOUT][DH]
  unsigned short* h   = (unsigned short*)ws;                               // [B][DH]

  hipFuncSetAttribute((const void*)gemm_w8p,
                      hipFuncAttributeMaxDynamicSharedMemorySize, 131072);
  hipFuncSetAttribute((const void*)gemm_w8<false>,
                      hipFuncAttributeMaxDynamicSharedMemorySize, 131072);

  int n4 = B * DIN / 4;
  cvt_f32_bf16<<<n4 / 256, 256, 0, stream>>>((const float4*)x, (ushort4*)xb, n4);
  transpose_f32_bf16<<<dim3(DH / 32, DIN / 32), dim3(32, 8), 0, stream>>>(W1, w1t, DIN, DH);
  transpose_f32_bf16<<<dim3(DOUT / 32, DH / 32), dim3(32, 8), 0, stream>>>(W2, w2t, DH, DOUT);

  // h = relu(x @ W1 + b1) : persistent, 256 wgs, 4 M-panels x 16 K-tiles
  gemm_w8p<<<dim3(256), 512, 131072, stream>>>(xb, w1t, b1, h, DIN, DH);
  // out = h @ W2 + b2     : M=16384, N=1024, K=4096 (NT=64), 256 wgs
  gemm_w8<false><<<dim3((B / 256) * (DOUT / 256)), 512, 131072, stream>>>(
      h, w2t, b2, out, B, DOUT, DH, 2);
}